// Round 7
// baseline (29166.385 us; speedup 1.0000x reference)
//
#include <hip/hip_runtime.h>
#include <math.h>

#define NB 8192
enum { ACT_NONE = 0, ACT_RELU = 1, ACT_TANH = 2 };

// ---------------------------------------------------------------------------
// fp64 tiled GEMM: C[rows,N](f64) = act(A[rows,K] @ W[K,N](f32) + bias(f32)
// + addsrc(f64)).  A f32 (exact upcast) or f64.
// BM=BN=64, BK=16, 128 threads, 8x4 micro-tile, stride-interleaved lanes
// (conflict-free LDS). Per-element arithmetic: single f64 acc, k ascending,
// hardware FMA — identical chain to the round-6 passing kernel.
// rows%64==0, K%16==0, N arbitrary (col-guarded).
// ---------------------------------------------------------------------------
template<typename TA, int ACT, bool HB, bool HA>
__global__ __launch_bounds__(128)
void dgemm_k(const TA* __restrict__ A, int lda,
             const float* __restrict__ W, int ldw,
             const float* __restrict__ bias,
             const double* __restrict__ addsrc, int ldadd,
             double* __restrict__ C, int ldc, int N, int K)
{
    __shared__ double As[16][64];
    __shared__ double Bs[16][64];
    const int tid = threadIdx.x;
    const int tx = tid & 15;          // output col group: c = tx + 16j
    const int ty = tid >> 4;          // 0..7, output row group: r = ty + 8i
    const size_t m0 = (size_t)blockIdx.y * 64;
    const int n0 = blockIdx.x * 64;
    const int lrow = tid & 63;        // loader lane
    const int lset = tid >> 6;        // 0..1 (k-half)

    double acc[8][4];
#pragma unroll
    for (int i = 0; i < 8; i++)
#pragma unroll
        for (int j = 0; j < 4; j++) acc[i][j] = 0.0;

    for (int kt = 0; kt < K; kt += 16) {
        {   // A tile: thread loads 8 consecutive k-elems of one row
            const TA* ap = A + (m0 + lrow) * (size_t)lda + kt + lset * 8;
#pragma unroll
            for (int e = 0; e < 8; e++)
                As[lset * 8 + e][lrow] = (double)ap[e];
        }
        {   // B tile: thread loads one col across 8 k-rows (coalesced in N)
            const int gc = n0 + lrow;
#pragma unroll
            for (int e = 0; e < 8; e++) {
                int krow = lset * 8 + e;
                Bs[krow][lrow] = (gc < N) ? (double)W[(size_t)(kt + krow) * ldw + gc] : 0.0;
            }
        }
        __syncthreads();
#pragma unroll
        for (int k = 0; k < 16; k++) {
            double a[8], b[4];
#pragma unroll
            for (int i = 0; i < 8; i++) a[i] = As[k][ty + 8 * i];
#pragma unroll
            for (int j = 0; j < 4; j++) b[j] = Bs[k][tx + 16 * j];
#pragma unroll
            for (int i = 0; i < 8; i++)
#pragma unroll
                for (int j = 0; j < 4; j++)
                    acc[i][j] = fma(a[i], b[j], acc[i][j]);
        }
        __syncthreads();
    }

#pragma unroll
    for (int i = 0; i < 8; i++) {
        size_t gr = m0 + ty + 8 * i;
#pragma unroll
        for (int j = 0; j < 4; j++) {
            int gc = n0 + tx + 16 * j;
            if (gc < N) {
                double v = acc[i][j];
                if (HB) v += (double)bias[gc];
                if (HA) v += addsrc[gr * (size_t)ldadd + gc];
                if (ACT == ACT_RELU) v = v > 0.0 ? v : 0.0;
                if (ACT == ACT_TANH) v = tanh(v);
                C[gr * (size_t)ldc + gc] = v;
            }
        }
    }
}

// msg = relu(W[idx] + b) in fp64
__global__ void msg_build_d(const float* __restrict__ Wt, const float* __restrict__ bias,
                            const int* __restrict__ idx, int istride, int ioff,
                            double* __restrict__ out, int ldo, int ooff)
{
    int b = blockIdx.x;
    int j = threadIdx.x;   // 256
    int id = idx[(size_t)b * istride + ioff];
    double v = (double)Wt[(size_t)id * 256 + j] + (double)bias[j];
    out[(size_t)b * ldo + ooff + j] = v > 0.0 ? v : 0.0;
}

// ---------------------------------------------------------------------------
// Fused Wo-GEMV + f64 softmax + f32-quantized stable top-k.
// Block = 256 threads handles 4 rows; thread t owns logit column t (t<N).
// logit[r][c] = sum_k h2[r][k]*W[k][c] (f64 FMA, k ascending) + bo[c] —
// identical per-element chain to the dgemm path of the passing round.
// Decisions on float(p) with strict-> and lower-index ties.
// ---------------------------------------------------------------------------
__global__ __launch_bounds__(256)
void wo_topk(const double* __restrict__ h2,   // [R,1024]
             const float* __restrict__ W,     // [1024,N] row-major
             const float* __restrict__ bo,
             int N, int k,
             float* __restrict__ sout, int sstride, int soff,
             int* __restrict__ iout, int istride, int ioff)
{
    __shared__ double h2s[4][1024];   // 32 KB
    __shared__ double dred[256];
    __shared__ float  pred[256];
    __shared__ int    ired[256];
    const int tid = threadIdx.x;
    const size_t rbase = (size_t)blockIdx.x * 4;

    for (int t = tid; t < 4096; t += 256)
        h2s[t >> 10][t & 1023] = h2[(rbase + (t >> 10)) * 1024 + (t & 1023)];
    __syncthreads();

    const int c = tid;
    double a0 = 0.0, a1 = 0.0, a2 = 0.0, a3 = 0.0;
    if (c < N) {
        for (int kk = 0; kk < 1024; kk++) {
            double w = (double)W[(size_t)kk * N + c];
            a0 = fma(h2s[0][kk], w, a0);
            a1 = fma(h2s[1][kk], w, a1);
            a2 = fma(h2s[2][kk], w, a2);
            a3 = fma(h2s[3][kk], w, a3);
        }
    }
    double lgv[4];
    double bb = (c < N) ? (double)bo[c] : 0.0;
    lgv[0] = a0 + bb; lgv[1] = a1 + bb; lgv[2] = a2 + bb; lgv[3] = a3 + bb;

    for (int r = 0; r < 4; r++) {
        // max (exact, order-free)
        dred[tid] = (c < N) ? lgv[r] : -INFINITY;
        __syncthreads();
        for (int s = 128; s; s >>= 1) {
            if (tid < s) dred[tid] = fmax(dred[tid], dred[tid + s]);
            __syncthreads();
        }
        double mx = dred[0];
        __syncthreads();
        // sum of exp (f64; order-robust under f32 quantization)
        double e = (c < N) ? exp(lgv[r] - mx) : 0.0;
        dred[tid] = e;
        __syncthreads();
        for (int s = 128; s; s >>= 1) {
            if (tid < s) dred[tid] += dred[tid + s];
            __syncthreads();
        }
        double se = dred[0];
        __syncthreads();
        float p = (c < N) ? (float)(e / se) : -1.f;

        for (int kk = 0; kk < k; kk++) {
            pred[tid] = p;
            ired[tid] = (c < N) ? c : (1 << 20);
            __syncthreads();
            for (int s = 128; s; s >>= 1) {
                if (tid < s) {
                    float ov = pred[tid + s]; int oi = ired[tid + s];
                    if (ov > pred[tid] || (ov == pred[tid] && oi < ired[tid])) {
                        pred[tid] = ov; ired[tid] = oi;
                    }
                }
                __syncthreads();
            }
            if (tid == 0) {
                size_t b = rbase + r;
                sout[b * sstride + soff + kk] = pred[0];
                iout[b * istride + ioff + kk] = ired[0];
            }
            int win = ired[0];
            __syncthreads();
            if (c == win) p = -1.f;
        }
    }
}

// joint scores: f32 left-assoc product chain, stable desc argsort, [15,5] ints
__global__ void finalize_q(const float* __restrict__ s0, const float* __restrict__ s1,
                           const float* __restrict__ s2, const float* __restrict__ s3,
                           const float* __restrict__ s4,
                           const int* __restrict__ i0, const int* __restrict__ i1,
                           const int* __restrict__ i2, const int* __restrict__ i3,
                           const int* __restrict__ i4,
                           int* __restrict__ out)
{
    int b = blockIdx.x * 256 + threadIdx.x;
    float sc[15];
    float a0 = s0[b];
    for (int t = 0; t < 15; t++) {
        int a = t / 5;
        float v = a0 * s1[b * 3 + a];
        v = v * s2[b * 3 + a];
        v = v * s3[b * 15 + t];
        v = v * s4[b * 15 + t];
        sc[t] = v;
    }
    bool used[15] = {false};
    for (int r = 0; r < 15; r++) {
        int best = -1; float bv = -INFINITY;
        for (int t = 0; t < 15; t++)
            if (!used[t] && sc[t] > bv) { bv = sc[t]; best = t; }
        used[best] = true;
        int a = best / 5;
        int* o = out + (size_t)b * 75 + r * 5;
        o[0] = i0[b];
        o[1] = i1[b * 3 + a];
        o[2] = i2[b * 3 + a];
        o[3] = i3[b * 15 + best];
        o[4] = i4[b * 15 + best];
    }
}

// ---------------- host-side dispatch ----------------
static void dgemm(hipStream_t st, int a_is_f32, const void* A, int lda,
                  const float* W, int ldw, const float* bias,
                  const double* add, int ldadd, double* C, int ldc,
                  int rows, int N, int K, int act)
{
    dim3 grid((N + 63) / 64, rows / 64);
#define LK(TA, AC, HBv, HAv) hipLaunchKernelGGL((dgemm_k<TA, AC, HBv, HAv>), grid, dim3(128), 0, st, \
        (const TA*)A, lda, W, ldw, bias, add, ldadd, C, ldc, N, K)
#define ACTS(TA, HBv, HAv) do { if (act == 0) LK(TA, 0, HBv, HAv); \
                                else if (act == 1) LK(TA, 1, HBv, HAv); \
                                else LK(TA, 2, HBv, HAv); } while (0)
#define BDISP(TA) do { if (bias) { if (add) ACTS(TA, true, true); else ACTS(TA, true, false); } \
                       else      { if (add) ACTS(TA, false, true); else ACTS(TA, false, false); } } while (0)
    if (a_is_f32) BDISP(float); else BDISP(double);
#undef BDISP
#undef ACTS
#undef LK
}

extern "C" void kernel_launch(void* const* d_in, const int* in_sizes, int n_in,
                              void* d_out, int out_size, void* d_ws, size_t ws_size,
                              hipStream_t stream)
{
    (void)in_sizes; (void)n_in; (void)out_size;
    const float* feat = (const float*)d_in[0];
    const float* Wc  = (const float*)d_in[1];
    const float* bc  = (const float*)d_in[2];
    const float* Ws1 = (const float*)d_in[3];
    const float* bs1 = (const float*)d_in[4];
    const float* Ws2 = (const float*)d_in[5];
    const float* bs2 = (const float*)d_in[6];
    const float* Wr  = (const float*)d_in[7];
    const float* br  = (const float*)d_in[8];
    auto Wh1 = [&](int i) { return (const float*)d_in[9 + 6 * i]; };
    auto bh1 = [&](int i) { return (const float*)d_in[10 + 6 * i]; };
    auto Wh2 = [&](int i) { return (const float*)d_in[11 + 6 * i]; };
    auto bh2 = [&](int i) { return (const float*)d_in[12 + 6 * i]; };
    auto Wo  = [&](int i) { return (const float*)d_in[13 + 6 * i]; };
    auto bo  = [&](int i) { return (const float*)d_in[14 + 6 * i]; };
    const int outs[5] = {54, 87, 87, 235, 235};

    // per-row: 6144 work doubles + 37 score floats + 37 ints = 49,448 B
    const size_t perRow = 6144ull * 8 + 37ull * 4 + 37ull * 4;
    int R = NB;
    while (R > 256 && (size_t)R * perRow > ws_size) R >>= 1;

    double* ws = (double*)d_ws;
    size_t off = 0;
    auto alloc = [&](size_t n) { double* p = ws + off; off += n; return p; };
    double* msg0 = alloc((size_t)R * 256);
    double* xm0  = alloc((size_t)R * 512);
    double* xm1  = alloc((size_t)R * 512);
    double* xm2  = alloc((size_t)R * 512);
    double* xms[3] = {xm0, xm1, xm2};
    double* bufC = alloc((size_t)R * 1024);
    double* base = alloc((size_t)R * 1024);
    double* h1   = alloc((size_t)R * 1024);
    double* h2   = alloc((size_t)R * 1024);
    double* m3   = alloc((size_t)R * 256);
    float* fbase = (float*)(ws + off);
    float* s0 = fbase;            float* s1 = fbase + R;
    float* s2 = s1 + 3 * R;       float* s3 = s2 + 3 * R;
    float* s4 = s3 + 15 * R;
    int* ibase = (int*)(s4 + 15 * R);
    int* i0 = ibase;              int* i1 = ibase + R;
    int* i2 = i1 + 3 * R;         int* i3 = i2 + 3 * R;
    int* i4 = i3 + 15 * R;

    dim3 wg(R / 4);

    for (int r0 = 0; r0 < NB; r0 += R) {
        const float* fC = feat + (size_t)r0 * 1024;

        // ---- stage 0 (K=1024) ----
        dgemm(stream, 1, fC, 1024, Wh1(0), 1024, bh1(0), nullptr, 0, h1, 1024, R, 1024, 1024, ACT_RELU);
        dgemm(stream, 0, h1, 1024, Wh2(0), 1024, bh2(0), nullptr, 0, h2, 1024, R, 1024, 1024, ACT_TANH);
        hipLaunchKernelGGL(wo_topk, wg, dim3(256), 0, stream, h2, Wo(0), bo(0), outs[0], 1, s0, 1, 0, i0, 1, 0);
        hipLaunchKernelGGL(msg_build_d, dim3(R), dim3(256), 0, stream, Wc, bc, i0, 1, 0, msg0, 256, 0);

        // ---- stage 1 (K=1280) ----
        dgemm(stream, 1, fC, 1024, Wh1(1), 1024, nullptr, nullptr, 0, bufC, 1024, R, 1024, 1024, ACT_NONE);
        dgemm(stream, 0, msg0, 256, Wh1(1) + (size_t)1024 * 1024, 1024, bh1(1), bufC, 1024, h1, 1024, R, 1024, 256, ACT_RELU);
        dgemm(stream, 0, h1, 1024, Wh2(1), 1024, bh2(1), nullptr, 0, h2, 1024, R, 1024, 1024, ACT_TANH);
        hipLaunchKernelGGL(wo_topk, wg, dim3(256), 0, stream, h2, Wo(1), bo(1), outs[1], 3, s1, 3, 0, i1, 3, 0);
        for (int a = 0; a < 3; a++)
            hipLaunchKernelGGL(msg_build_d, dim3(R), dim3(256), 0, stream, Ws1, bs1, i1, 3, a, xms[a], 512, 0);

        // ---- stage 2 (K=1536) ----
        dgemm(stream, 1, fC, 1024, Wh1(2), 1024, nullptr, nullptr, 0, bufC, 1024, R, 1024, 1024, ACT_NONE);
        dgemm(stream, 0, msg0, 256, Wh1(2) + (size_t)1024 * 1024, 1024, nullptr, bufC, 1024, bufC, 1024, R, 1024, 256, ACT_NONE);
        for (int a = 0; a < 3; a++) {
            dgemm(stream, 0, xms[a], 512, Wh1(2) + (size_t)1280 * 1024, 1024, bh1(2), bufC, 1024, h1, 1024, R, 1024, 256, ACT_RELU);
            dgemm(stream, 0, h1, 1024, Wh2(2), 1024, bh2(2), nullptr, 0, h2, 1024, R, 1024, 1024, ACT_TANH);
            hipLaunchKernelGGL(wo_topk, wg, dim3(256), 0, stream, h2, Wo(2), bo(2), outs[2], 1, s2, 3, a, i2, 3, a);
        }
        for (int a = 0; a < 3; a++)
            hipLaunchKernelGGL(msg_build_d, dim3(R), dim3(256), 0, stream, Ws2, bs2, i2, 3, a, xms[a], 512, 256);

        // ---- stage 3 (K=1792) ----
        dgemm(stream, 1, fC, 1024, Wh1(3), 1024, nullptr, nullptr, 0, bufC, 1024, R, 1024, 1024, ACT_NONE);
        dgemm(stream, 0, msg0, 256, Wh1(3) + (size_t)1024 * 1024, 1024, nullptr, bufC, 1024, bufC, 1024, R, 1024, 256, ACT_NONE);
        for (int a = 0; a < 3; a++) {
            dgemm(stream, 0, xms[a], 512, Wh1(3) + (size_t)1280 * 1024, 1024, bh1(3), bufC, 1024, h1, 1024, R, 1024, 512, ACT_RELU);
            dgemm(stream, 0, h1, 1024, Wh2(3), 1024, bh2(3), nullptr, 0, h2, 1024, R, 1024, 1024, ACT_TANH);
            hipLaunchKernelGGL(wo_topk, wg, dim3(256), 0, stream, h2, Wo(3), bo(3), outs[3], 5, s3, 15, 5 * a, i3, 15, 5 * a);
        }

        // ---- stage 4 (K=2048) ----
        dgemm(stream, 1, fC, 1024, Wh1(4), 1024, nullptr, nullptr, 0, bufC, 1024, R, 1024, 1024, ACT_NONE);
        dgemm(stream, 0, msg0, 256, Wh1(4) + (size_t)1024 * 1024, 1024, nullptr, bufC, 1024, bufC, 1024, R, 1024, 256, ACT_NONE);
        for (int a = 0; a < 3; a++) {
            dgemm(stream, 0, xms[a], 512, Wh1(4) + (size_t)1280 * 1024, 1024, nullptr, bufC, 1024, base, 1024, R, 1024, 512, ACT_NONE);
            for (int c = 0; c < 5; c++) {
                int t = a * 5 + c;
                hipLaunchKernelGGL(msg_build_d, dim3(R), dim3(256), 0, stream, Wr, br, i3, 15, t, m3, 256, 0);
                dgemm(stream, 0, m3, 256, Wh1(4) + (size_t)1792 * 1024, 1024, bh1(4), base, 1024, h1, 1024, R, 1024, 256, ACT_RELU);
                dgemm(stream, 0, h1, 1024, Wh2(4), 1024, bh2(4), nullptr, 0, h2, 1024, R, 1024, 1024, ACT_TANH);
                hipLaunchKernelGGL(wo_topk, wg, dim3(256), 0, stream, h2, Wo(4), bo(4), outs[4], 1, s4, 15, t, i4, 15, t);
            }
        }

        // ---- final join + stable descending argsort on f32 products ----
        hipLaunchKernelGGL(finalize_q, dim3(R / 256), dim3(256), 0, stream,
                           s0, s1, s2, s3, s4, i0, i1, i2, i3, i4, (int*)d_out + (size_t)r0 * 75);
    }
}

// Round 8
// 21968.730 us; speedup vs baseline: 1.3276x; 1.3276x over previous
//
#include <hip/hip_runtime.h>
#include <math.h>

#define NB 8192
enum { ACT_NONE = 0, ACT_RELU = 1, ACT_TANH = 2 };

typedef double d4_t __attribute__((ext_vector_type(4)));

// ---------------------------------------------------------------------------
// f64 MFMA GEMM: C[rows,1024](f64) = act(A[rows,K] @ W[K,1024](f32) + bias
// + addsrc). A f32 (exact upcast) or f64. Tile 128x128, BK=16, 256 thr =
// 4 waves (2x2 of 64x64), v_mfma_f64_16x16x4_f64, 16 d4 accs/thread.
// All strides (W,addsrc,C) = 1024. rows%128==0, K%16==0.
// Accuracy: IEEE f64 MFMA chain, K ascending in 4-chunks — decision-grade
// (~1e-15 rel); decisions stay f32-quantized+stable-tie downstream.
// ---------------------------------------------------------------------------
template<typename TA, int ACT, bool HB, bool HA>
__global__ __launch_bounds__(256)
void mgemm_k(const TA* __restrict__ A, int lda,
             const float* __restrict__ W,
             const float* __restrict__ bias,
             const double* __restrict__ addsrc,
             double* __restrict__ C, int K)
{
    __shared__ double Al[16][129];   // [k][m], pad->conflict-free xpose writes
    __shared__ double Bl[16][128];   // [k][n]
    const int tid  = threadIdx.x;
    const int lane = tid & 63;
    const int w    = tid >> 6;           // wave 0..3
    const int q    = lane >> 4;          // MFMA k index 0..3
    const int c    = lane & 15;          // MFMA row/col-in-16
    const int m0w  = (w >> 1) * 64;
    const int n0w  = (w & 1) * 64;
    const size_t m0 = (size_t)blockIdx.y * 128;
    const int    n0 = blockIdx.x * 128;

    const int srow  = tid >> 1;          // A-stage: row 0..127
    const int shalf = tid & 1;           // A-stage: k-half (8 elems)
    const int bk    = tid >> 4;          // B-stage: k-row 0..15
    const int bseg  = tid & 15;          // B-stage: col seg

    d4_t acc[4][4];
#pragma unroll
    for (int i = 0; i < 4; i++)
#pragma unroll
        for (int j = 0; j < 4; j++) acc[i][j] = (d4_t){0.0, 0.0, 0.0, 0.0};

    for (int kt = 0; kt < K; kt += 16) {
        {   // A tile: thread loads 8 consecutive k of one row, xpose to [k][m]
            const TA* ap = A + (m0 + srow) * (size_t)lda + kt + shalf * 8;
#pragma unroll
            for (int e = 0; e < 8; e++)
                Al[shalf * 8 + e][srow] = (double)ap[e];
        }
        {   // B tile: thread covers cols {bseg+16e} of one k-row
            const float* wp = W + (size_t)(kt + bk) * 1024 + n0 + bseg;
#pragma unroll
            for (int e = 0; e < 8; e++)
                Bl[bk][bseg + 16 * e] = (double)wp[16 * e];
        }
        __syncthreads();
#pragma unroll
        for (int kk = 0; kk < 4; kk++) {
            double a[4], b[4];
#pragma unroll
            for (int i = 0; i < 4; i++) a[i] = Al[kk * 4 + q][m0w + i * 16 + c];
#pragma unroll
            for (int j = 0; j < 4; j++) b[j] = Bl[kk * 4 + q][n0w + j * 16 + c];
#pragma unroll
            for (int i = 0; i < 4; i++)
#pragma unroll
                for (int j = 0; j < 4; j++)
                    acc[i][j] = __builtin_amdgcn_mfma_f64_16x16x4f64(
                        a[i], b[j], acc[i][j], 0, 0, 0);
        }
        __syncthreads();
    }

#pragma unroll
    for (int i = 0; i < 4; i++)
#pragma unroll
        for (int j = 0; j < 4; j++)
#pragma unroll
            for (int v = 0; v < 4; v++) {
                size_t gr = m0 + m0w + i * 16 + q * 4 + v;
                int    gc = n0 + n0w + j * 16 + c;
                double val = acc[i][j][v];
                if (HB) val += (double)bias[gc];
                if (HA) val += addsrc[gr * 1024 + gc];
                if (ACT == ACT_RELU) val = val > 0.0 ? val : 0.0;
                if (ACT == ACT_TANH) val = tanh(val);
                C[gr * 1024 + gc] = val;
            }
}

// msg = relu(W[idx] + b) in fp64
__global__ void msg_build_d(const float* __restrict__ Wt, const float* __restrict__ bias,
                            const int* __restrict__ idx, int istride, int ioff,
                            double* __restrict__ out, int ldo, int ooff)
{
    int b = blockIdx.x;
    int j = threadIdx.x;   // 256
    int id = idx[(size_t)b * istride + ioff];
    double v = (double)Wt[(size_t)id * 256 + j] + (double)bias[j];
    out[(size_t)b * ldo + ooff + j] = v > 0.0 ? v : 0.0;
}

// ---------------------------------------------------------------------------
// Fused Wo-GEMV + f64 softmax + f32-quantized stable top-k. 8 rows/block.
// Thread t owns logit column t (t<N); 8 independent f64 FMA chains.
// ---------------------------------------------------------------------------
__global__ __launch_bounds__(256)
void wo_topk(const double* __restrict__ h2,   // [R,1024]
             const float* __restrict__ W,     // [1024,N] row-major
             const float* __restrict__ bo,
             int N, int k,
             float* __restrict__ sout, int sstride, int soff,
             int* __restrict__ iout, int istride, int ioff)
{
    __shared__ double h2s[8][1024];   // 64 KB
    __shared__ double dred[256];
    __shared__ float  pred[256];
    __shared__ int    ired[256];
    const int tid = threadIdx.x;
    const size_t rbase = (size_t)blockIdx.x * 8;

    for (int t = tid; t < 8192; t += 256)
        h2s[t >> 10][t & 1023] = h2[(rbase + (t >> 10)) * 1024 + (t & 1023)];
    __syncthreads();

    const int c = tid;
    double a[8] = {0, 0, 0, 0, 0, 0, 0, 0};
    if (c < N) {
        for (int kk = 0; kk < 1024; kk++) {
            double wv = (double)W[(size_t)kk * N + c];
#pragma unroll
            for (int r = 0; r < 8; r++)
                a[r] = fma(h2s[r][kk], wv, a[r]);
        }
    }
    double bb = (c < N) ? (double)bo[c] : 0.0;

    for (int r = 0; r < 8; r++) {
        double lgv = a[r] + bb;
        dred[tid] = (c < N) ? lgv : -INFINITY;
        __syncthreads();
        for (int s = 128; s; s >>= 1) {
            if (tid < s) dred[tid] = fmax(dred[tid], dred[tid + s]);
            __syncthreads();
        }
        double mx = dred[0];
        __syncthreads();
        double e = (c < N) ? exp(lgv - mx) : 0.0;
        dred[tid] = e;
        __syncthreads();
        for (int s = 128; s; s >>= 1) {
            if (tid < s) dred[tid] += dred[tid + s];
            __syncthreads();
        }
        double se = dred[0];
        __syncthreads();
        float p = (c < N) ? (float)(e / se) : -1.f;

        for (int kk = 0; kk < k; kk++) {
            pred[tid] = p;
            ired[tid] = (c < N) ? c : (1 << 20);
            __syncthreads();
            for (int s = 128; s; s >>= 1) {
                if (tid < s) {
                    float ov = pred[tid + s]; int oi = ired[tid + s];
                    if (ov > pred[tid] || (ov == pred[tid] && oi < ired[tid])) {
                        pred[tid] = ov; ired[tid] = oi;
                    }
                }
                __syncthreads();
            }
            if (tid == 0) {
                size_t b = rbase + r;
                sout[b * sstride + soff + kk] = pred[0];
                iout[b * istride + ioff + kk] = ired[0];
            }
            int win = ired[0];
            __syncthreads();
            if (c == win) p = -1.f;
        }
    }
}

// joint scores: f32 left-assoc product chain, stable desc argsort, [15,5] ints
__global__ void finalize_q(const float* __restrict__ s0, const float* __restrict__ s1,
                           const float* __restrict__ s2, const float* __restrict__ s3,
                           const float* __restrict__ s4,
                           const int* __restrict__ i0, const int* __restrict__ i1,
                           const int* __restrict__ i2, const int* __restrict__ i3,
                           const int* __restrict__ i4,
                           int* __restrict__ out)
{
    int b = blockIdx.x * 256 + threadIdx.x;
    float sc[15];
    float a0 = s0[b];
    for (int t = 0; t < 15; t++) {
        int a = t / 5;
        float v = a0 * s1[b * 3 + a];
        v = v * s2[b * 3 + a];
        v = v * s3[b * 15 + t];
        v = v * s4[b * 15 + t];
        sc[t] = v;
    }
    bool used[15] = {false};
    for (int r = 0; r < 15; r++) {
        int best = -1; float bv = -INFINITY;
        for (int t = 0; t < 15; t++)
            if (!used[t] && sc[t] > bv) { bv = sc[t]; best = t; }
        used[best] = true;
        int a = best / 5;
        int* o = out + (size_t)b * 75 + r * 5;
        o[0] = i0[b];
        o[1] = i1[b * 3 + a];
        o[2] = i2[b * 3 + a];
        o[3] = i3[b * 15 + best];
        o[4] = i4[b * 15 + best];
    }
}

// ---------------- host-side dispatch ----------------
static void dgemm(hipStream_t st, int a_is_f32, const void* A, int lda,
                  const float* W, const float* bias,
                  const double* add, double* C,
                  int rows, int K, int act)
{
    dim3 grid(8, rows / 128);
#define LK(TA, AC, HBv, HAv) hipLaunchKernelGGL((mgemm_k<TA, AC, HBv, HAv>), grid, dim3(256), 0, st, \
        (const TA*)A, lda, W, bias, add, C, K)
#define ACTS(TA, HBv, HAv) do { if (act == 0) LK(TA, 0, HBv, HAv); \
                                else if (act == 1) LK(TA, 1, HBv, HAv); \
                                else LK(TA, 2, HBv, HAv); } while (0)
#define BDISP(TA) do { if (bias) { if (add) ACTS(TA, true, true); else ACTS(TA, true, false); } \
                       else      { if (add) ACTS(TA, false, true); else ACTS(TA, false, false); } } while (0)
    if (a_is_f32) BDISP(float); else BDISP(double);
#undef BDISP
#undef ACTS
#undef LK
}

extern "C" void kernel_launch(void* const* d_in, const int* in_sizes, int n_in,
                              void* d_out, int out_size, void* d_ws, size_t ws_size,
                              hipStream_t stream)
{
    (void)in_sizes; (void)n_in; (void)out_size;
    const float* feat = (const float*)d_in[0];
    const float* Wc  = (const float*)d_in[1];
    const float* bc  = (const float*)d_in[2];
    const float* Ws1 = (const float*)d_in[3];
    const float* bs1 = (const float*)d_in[4];
    const float* Ws2 = (const float*)d_in[5];
    const float* bs2 = (const float*)d_in[6];
    const float* Wr  = (const float*)d_in[7];
    const float* br  = (const float*)d_in[8];
    auto Wh1 = [&](int i) { return (const float*)d_in[9 + 6 * i]; };
    auto bh1 = [&](int i) { return (const float*)d_in[10 + 6 * i]; };
    auto Wh2 = [&](int i) { return (const float*)d_in[11 + 6 * i]; };
    auto bh2 = [&](int i) { return (const float*)d_in[12 + 6 * i]; };
    auto Wo  = [&](int i) { return (const float*)d_in[13 + 6 * i]; };
    auto bo  = [&](int i) { return (const float*)d_in[14 + 6 * i]; };
    const int outs[5] = {54, 87, 87, 235, 235};

    // per-row: 6144 work doubles + 37 score floats + 37 ints
    const size_t perRow = 6144ull * 8 + 37ull * 4 + 37ull * 4;
    int R = NB;
    while (R > 256 && (size_t)R * perRow > ws_size) R >>= 1;

    double* ws = (double*)d_ws;
    size_t off = 0;
    auto alloc = [&](size_t n) { double* p = ws + off; off += n; return p; };
    double* msg0 = alloc((size_t)R * 256);
    double* xm0  = alloc((size_t)R * 512);
    double* xm1  = alloc((size_t)R * 512);
    double* xm2  = alloc((size_t)R * 512);
    double* xms[3] = {xm0, xm1, xm2};
    double* bufC = alloc((size_t)R * 1024);
    double* base = alloc((size_t)R * 1024);
    double* h1   = alloc((size_t)R * 1024);
    double* h2   = alloc((size_t)R * 1024);
    double* m3   = alloc((size_t)R * 256);
    float* fbase = (float*)(ws + off);
    float* s0 = fbase;            float* s1 = fbase + R;
    float* s2 = s1 + 3 * R;       float* s3 = s2 + 3 * R;
    float* s4 = s3 + 15 * R;
    int* ibase = (int*)(s4 + 15 * R);
    int* i0 = ibase;              int* i1 = ibase + R;
    int* i2 = i1 + 3 * R;         int* i3 = i2 + 3 * R;
    int* i4 = i3 + 15 * R;

    dim3 wg(R / 8);

    for (int r0 = 0; r0 < NB; r0 += R) {
        const float* fC = feat + (size_t)r0 * 1024;

        // ---- stage 0 (K=1024) ----
        dgemm(stream, 1, fC, 1024, Wh1(0), bh1(0), nullptr, h1, R, 1024, ACT_RELU);
        dgemm(stream, 0, h1, 1024, Wh2(0), bh2(0), nullptr, h2, R, 1024, ACT_TANH);
        hipLaunchKernelGGL(wo_topk, wg, dim3(256), 0, stream, h2, Wo(0), bo(0), outs[0], 1, s0, 1, 0, i0, 1, 0);
        hipLaunchKernelGGL(msg_build_d, dim3(R), dim3(256), 0, stream, Wc, bc, i0, 1, 0, msg0, 256, 0);

        // ---- stage 1 (K=1280) ----
        dgemm(stream, 1, fC, 1024, Wh1(1), nullptr, nullptr, bufC, R, 1024, ACT_NONE);
        dgemm(stream, 0, msg0, 256, Wh1(1) + (size_t)1024 * 1024, bh1(1), bufC, h1, R, 256, ACT_RELU);
        dgemm(stream, 0, h1, 1024, Wh2(1), bh2(1), nullptr, h2, R, 1024, ACT_TANH);
        hipLaunchKernelGGL(wo_topk, wg, dim3(256), 0, stream, h2, Wo(1), bo(1), outs[1], 3, s1, 3, 0, i1, 3, 0);
        for (int a = 0; a < 3; a++)
            hipLaunchKernelGGL(msg_build_d, dim3(R), dim3(256), 0, stream, Ws1, bs1, i1, 3, a, xms[a], 512, 0);

        // ---- stage 2 (K=1536) ----
        dgemm(stream, 1, fC, 1024, Wh1(2), nullptr, nullptr, bufC, R, 1024, ACT_NONE);
        dgemm(stream, 0, msg0, 256, Wh1(2) + (size_t)1024 * 1024, nullptr, bufC, bufC, R, 256, ACT_NONE);
        for (int a = 0; a < 3; a++) {
            dgemm(stream, 0, xms[a], 512, Wh1(2) + (size_t)1280 * 1024, bh1(2), bufC, h1, R, 256, ACT_RELU);
            dgemm(stream, 0, h1, 1024, Wh2(2), bh2(2), nullptr, h2, R, 1024, ACT_TANH);
            hipLaunchKernelGGL(wo_topk, wg, dim3(256), 0, stream, h2, Wo(2), bo(2), outs[2], 1, s2, 3, a, i2, 3, a);
        }
        for (int a = 0; a < 3; a++)
            hipLaunchKernelGGL(msg_build_d, dim3(R), dim3(256), 0, stream, Ws2, bs2, i2, 3, a, xms[a], 512, 256);

        // ---- stage 3 (K=1792) ----
        dgemm(stream, 1, fC, 1024, Wh1(3), nullptr, nullptr, bufC, R, 1024, ACT_NONE);
        dgemm(stream, 0, msg0, 256, Wh1(3) + (size_t)1024 * 1024, nullptr, bufC, bufC, R, 256, ACT_NONE);
        for (int a = 0; a < 3; a++) {
            dgemm(stream, 0, xms[a], 512, Wh1(3) + (size_t)1280 * 1024, bh1(3), bufC, h1, R, 512, ACT_RELU);
            dgemm(stream, 0, h1, 1024, Wh2(3), bh2(3), nullptr, h2, R, 1024, ACT_TANH);
            hipLaunchKernelGGL(wo_topk, wg, dim3(256), 0, stream, h2, Wo(3), bo(3), outs[3], 5, s3, 15, 5 * a, i3, 15, 5 * a);
        }

        // ---- stage 4 (K=2048) ----
        dgemm(stream, 1, fC, 1024, Wh1(4), nullptr, nullptr, bufC, R, 1024, ACT_NONE);
        dgemm(stream, 0, msg0, 256, Wh1(4) + (size_t)1024 * 1024, nullptr, bufC, bufC, R, 256, ACT_NONE);
        for (int a = 0; a < 3; a++) {
            dgemm(stream, 0, xms[a], 512, Wh1(4) + (size_t)1280 * 1024, nullptr, bufC, base, R, 512, ACT_NONE);
            for (int c = 0; c < 5; c++) {
                int t = a * 5 + c;
                hipLaunchKernelGGL(msg_build_d, dim3(R), dim3(256), 0, stream, Wr, br, i3, 15, t, m3, 256, 0);
                dgemm(stream, 0, m3, 256, Wh1(4) + (size_t)1792 * 1024, bh1(4), base, h1, R, 256, ACT_RELU);
                dgemm(stream, 0, h1, 1024, Wh2(4), bh2(4), nullptr, h2, R, 1024, ACT_TANH);
                hipLaunchKernelGGL(wo_topk, wg, dim3(256), 0, stream, h2, Wo(4), bo(4), outs[4], 1, s4, 15, t, i4, 15, t);
            }
        }

        // ---- final join + stable descending argsort on f32 products ----
        hipLaunchKernelGGL(finalize_q, dim3(R / 256), dim3(256), 0, stream,
                           s0, s1, s2, s3, s4, i0, i1, i2, i3, i4, (int*)d_out + (size_t)r0 * 75);
    }
}